// Round 3
// baseline (206.721 us; speedup 1.0000x reference)
//
#include <hip/hip_runtime.h>
#include <hip/hip_cooperative_groups.h>
#include <math.h>

namespace cg = cooperative_groups;

#define N_    1024
#define RANK_ 8
#define M_    8192

typedef float vf2 __attribute__((ext_vector_type(2)));

// Static device scratch, fully rewritten every call.
__device__ __align__(16) float2 g_Y   [RANK_ * M_];      // DFT stage-1 intermediate
__device__ __align__(16) float2 g_HreP[(RANK_/2) * M_];  // {Re Hf[2p][m], Re Hf[2p+1][m]}
__device__ __align__(16) float2 g_HimP[(RANK_/2) * M_];  // {Im Hf[2p][m], Im Hf[2p+1][m]}
__device__ __align__(16) float  g_sw  [N_ * RANK_];      // softmax(W, axis=1)
__device__ __align__(16) float2 g_step[N_ * RANK_];      // {cos,sin}(2pi*tau/32): rotor m-step factor

// v_sin_f32 / v_cos_f32: input in REVOLUTIONS (cdna4_isa.md §3); reduce via fract.
__device__ __forceinline__ float cos2pi(float rev) { return __builtin_amdgcn_cosf(rev); }
__device__ __forceinline__ float sin2pi(float rev) { return __builtin_amdgcn_sinf(rev); }
__device__ __forceinline__ float fractf_(float x)  { return __builtin_amdgcn_fractf(x); }

// ---------- phase 1: softplus -> stage-1 DFT (blk 0..255) + softmax/step table (blk 256..259) ----------
// stage 1: Y[r][t1][k2] = sum_t2 softplus(H)[r][t1+64*t2] * W128^(k2*t2),  8192 = 64(t1) x 128(t2)
__device__ __forceinline__ void do_pre(int blk, int t,
                                       const float* __restrict__ H,
                                       const float* __restrict__ W,
                                       const float* __restrict__ tau,
                                       float* spl, float* cs, float* sn_) {
    if (blk < 256) {
        int r    = blk >> 5;
        int half = t >> 7;                  // wave-uniform
        int j    = t & 127;
        int t1   = ((blk & 31) << 1) | half;
        float x = H[r * M_ + t1 + (j << 6)];
        spl[half * 128 + j] = (x > 20.f) ? x : log1pf(expf(x));
        if (t < 128) {
            float rev = (float)t * (1.0f / 128.0f);
            cs[t]  = cos2pi(rev);
            sn_[t] = sin2pi(rev);
        }
        __syncthreads();
        float ar = 0.f, ai = 0.f;
        for (int t2 = 0; t2 < 128; ++t2) {
            float xv = spl[half * 128 + t2];          // wave-uniform -> LDS broadcast
            int id = (j * t2) & 127;
            ar = fmaf(xv,  cs[id],  ar);              // x * (c - i s)
            ai = fmaf(xv, -sn_[id], ai);
        }
        g_Y[blk * 256 + t] = make_float2(ar, ai);     // == g_Y[r*8192 + t1*128 + k2]
    } else if (blk < 260) {
        int n = (blk - 256) * 256 + t;                // exactly covers n in [0,1024)
        float v[RANK_];
        float mx = -1e30f;
#pragma unroll
        for (int r = 0; r < RANK_; ++r) { v[r] = W[n * RANK_ + r]; mx = fmaxf(mx, v[r]); }
        float s = 0.f;
#pragma unroll
        for (int r = 0; r < RANK_; ++r) { v[r] = expf(v[r] - mx); s += v[r]; }
        float inv = 1.f / s;
#pragma unroll
        for (int r = 0; r < RANK_; ++r) g_sw[n * RANK_ + r] = v[r] * inv;
#pragma unroll
        for (int r = 0; r < RANK_; ++r) {
            float d  = tau[n * RANK_ + r] * (1.0f / 32.0f);   // 256/8192 rev per m-step
            float fr = fractf_(d);
            g_step[n * RANK_ + r] = make_float2(cos2pi(fr), sin2pi(fr));
        }
    }
}

// ---------- phase 2: stage-2 DFT, rotor recurrence; rectangular pair-layout output ----------
// Hf[r][k] = sum_t1 Y[r][t1][k&127] * e^{-2pi*i*t1*k/8192}
__device__ __forceinline__ void do_dft2(int tid) {
    int k = tid & 8191;
    int r = tid >> 13;
    int j = k & 127;
    const float2* y = g_Y + r * M_ + j;
    float rev = (float)k * (1.0f / 8192.0f);           // exact in fp32
    float cr = cos2pi(rev), sr = sin2pi(rev);
    float c = 1.f, s = 0.f;                            // rotor at t1 = 0
    float ar = 0.f, ai = 0.f;
    for (int t1 = 0; t1 < 64; ++t1) {
        float2 yv = y[t1 * 128];                       // coalesced (lanes j-consecutive)
        ar = fmaf(yv.x, c, ar); ar = fmaf(yv.y, s, ar);
        ai = fmaf(yv.y, c, ai); ai = fmaf(-yv.x, s, ai);
        float cn  = fmaf(c, cr, -(s * sr));
        float sn2 = fmaf(s, cr,  (c * sr));
        c = cn; s = sn2;
    }
    int p = r >> 1, h = r & 1;                         // pair-of-r layout
    reinterpret_cast<float*>(g_HreP)[((p * M_ + k) << 1) | h] = ar;
    reinterpret_cast<float*>(g_HimP)[((p * M_ + k) << 1) | h] = ai;
}

// ---------- phase 3 unit: NT=2 rows x 2048 m, rotor recurrence, zero trans in steady loop ----------
// unit u in [0,2048): bx = u&3 (m-chunk of 2048), ny = u>>2 (row pair). Thread owns m = bx*2048+t+256*s.
__device__ __forceinline__ void do_main_unit(int u, int t,
                                             const float* __restrict__ tau,
                                             float* __restrict__ out,
                                             int out_size_floats) {
    int bx  = u & 3;
    int ny  = u >> 2;
    int m_t = bx * 2048 + t;
    int n0  = ny * 2;
    float fm = (float)m_t * (1.0f / 8192.0f);

    vf2 Pr2[2][4], Pi2[2][4], dc2[2][4], ds2[2][4];
#pragma unroll
    for (int i = 0; i < 2; ++i) {
        int nb = (n0 + i) * RANK_;
        const float4* tp = reinterpret_cast<const float4*>(&tau[nb]);
        float4 ta = tp[0], tb = tp[1];
        const float4* wp = reinterpret_cast<const float4*>(&g_sw[nb]);
        float4 wa = wp[0], wb = wp[1];
        float tv[RANK_] = {ta.x, ta.y, ta.z, ta.w, tb.x, tb.y, tb.z, tb.w};
        float wv[RANK_] = {wa.x, wa.y, wa.z, wa.w, wb.x, wb.y, wb.z, wb.w};
#pragma unroll
        for (int p = 0; p < 4; ++p) {
            float2 s0 = g_step[nb + 2 * p];
            float2 s1 = g_step[nb + 2 * p + 1];
            dc2[i][p] = (vf2){s0.x, s1.x};
            ds2[i][p] = (vf2){s0.y, s1.y};
            float th0 = fractf_(tv[2 * p]     * fm);
            float th1 = fractf_(tv[2 * p + 1] * fm);
            Pr2[i][p] = (vf2){ wv[2 * p] * cos2pi(th0),  wv[2 * p + 1] * cos2pi(th1)};
            Pi2[i][p] = (vf2){-wv[2 * p] * sin2pi(th0), -wv[2 * p + 1] * sin2pi(th1)};
        }
    }

#pragma unroll
    for (int s = 0; s < 8; ++s) {
        int m = m_t + (s << 8);
        vf2 hre[4], him[4];
#pragma unroll
        for (int p = 0; p < 4; ++p) {
            float2 a = g_HreP[p * M_ + m];
            float2 b = g_HimP[p * M_ + m];
            hre[p] = (vf2){a.x, a.y};
            him[p] = (vf2){b.x, b.y};
        }
#pragma unroll
        for (int i = 0; i < 2; ++i) {
            vf2 aA = (vf2){0.f, 0.f}, aB = (vf2){0.f, 0.f};
#pragma unroll
            for (int p = 0; p < 4; ++p) {
                aA = __builtin_elementwise_fma(Pr2[i][p], hre[p], aA);  // += Pr*Hre
                aB = __builtin_elementwise_fma(Pi2[i][p], him[p], aB);  // += Pi*Him
            }
            float res = (aA.x + aA.y) - (aB.x + aB.y);                  // Re(P*Hf) over r
            int idx = (n0 + i) * M_ + m;
            if (idx < out_size_floats) out[idx] = res;
        }
        if (s < 7) {
            // P *= (dc - i*ds):  Pr' = Pr*dc + Pi*ds ; Pi' = Pi*dc - Pr*ds
#pragma unroll
            for (int i = 0; i < 2; ++i)
#pragma unroll
                for (int p = 0; p < 4; ++p) {
                    vf2 npr = __builtin_elementwise_fma(Pr2[i][p], dc2[i][p], Pi2[i][p] * ds2[i][p]);
                    vf2 npi = __builtin_elementwise_fma(Pi2[i][p], dc2[i][p], -(Pr2[i][p] * ds2[i][p]));
                    Pr2[i][p] = npr; Pi2[i][p] = npi;
                }
        }
    }
}

// ================= fused single-launch cooperative kernel =================
// 512 blocks x 256 threads: co-residency needs only 2 blocks/CU (safe at any VGPR<=256, LDS 2KB).
__global__ __launch_bounds__(256) void k_all(const float* __restrict__ H,
                                             const float* __restrict__ W,
                                             const float* __restrict__ tau,
                                             float* __restrict__ out,
                                             int out_size_floats) {
    __shared__ float spl[256];
    __shared__ float cs[128], sn_[128];
    cg::grid_group grid = cg::this_grid();
    int blk = blockIdx.x;
    int t   = threadIdx.x;

    do_pre(blk, t, H, W, tau, spl, cs, sn_);   // blk >= 260: no-op
    grid.sync();
    if (blk < 256) do_dft2(blk * 256 + t);
    grid.sync();
    for (int q = 0; q < 4; ++q)                 // 2048 units over 512 blocks, perfectly even
        do_main_unit(blk + 512 * q, t, tau, out, out_size_floats);
}

// ================= split fallback (used only if cooperative launch is rejected) =================
__global__ __launch_bounds__(256) void k_pre_s(const float* __restrict__ H,
                                               const float* __restrict__ W,
                                               const float* __restrict__ tau) {
    __shared__ float spl[256];
    __shared__ float cs[128], sn_[128];
    do_pre(blockIdx.x, threadIdx.x, H, W, tau, spl, cs, sn_);
}
__global__ __launch_bounds__(256) void k_dft2_s() {
    do_dft2(blockIdx.x * 256 + threadIdx.x);
}
__global__ __launch_bounds__(256) void k_main_s(const float* __restrict__ tau,
                                                float* __restrict__ out,
                                                int out_size_floats) {
    do_main_unit(blockIdx.x, threadIdx.x, tau, out, out_size_floats);
}

extern "C" void kernel_launch(void* const* d_in, const int* in_sizes, int n_in,
                              void* d_out, int out_size, void* d_ws, size_t ws_size,
                              hipStream_t stream) {
    const float* W   = (const float*)d_in[0];   // (N, RANK)
    const float* H   = (const float*)d_in[1];   // (RANK, M)
    const float* tau = (const float*)d_in[2];   // (N, RANK)
    float* out = (float*)d_out;
    int osf = out_size;                         // generous guard (bytes >= floats); stores structurally in-bounds

    void* args[] = {(void*)&H, (void*)&W, (void*)&tau, (void*)&out, (void*)&osf};
    hipError_t e = hipLaunchCooperativeKernel(reinterpret_cast<const void*>(k_all),
                                              dim3(512), dim3(256), args, 0, stream);
    if (e != hipSuccess) {
        // fallback: classic 3-launch pipeline (identical math)
        k_pre_s <<<dim3(260),  dim3(256), 0, stream>>>(H, W, tau);
        k_dft2_s<<<dim3(256),  dim3(256), 0, stream>>>();
        k_main_s<<<dim3(2048), dim3(256), 0, stream>>>(tau, out, osf);
    }
}

// Round 4
// 86.597 us; speedup vs baseline: 2.3872x; 2.3872x over previous
//
#include <hip/hip_runtime.h>
#include <math.h>

#define N_    1024
#define RANK_ 8
#define M_    8192

typedef float vf2 __attribute__((ext_vector_type(2)));

// Static device scratch (~1.1 MB), fully rewritten every call.
__device__ __align__(16) float2 g_Y  [RANK_ * M_];  // DFT stage-1 intermediate
__device__ __align__(16) float  g_Amp[RANK_ * M_];  // |FFT(softplus(H))|
__device__ __align__(16) float  g_Phi[RANK_ * M_];  // arg(FFT)/2pi  (revolutions)
__device__ __align__(16) float  g_sw [N_ * RANK_];  // softmax(W, axis=1)

// v_sin_f32 / v_cos_f32: input in REVOLUTIONS (cdna4_isa.md §3); reduce via fract.
__device__ __forceinline__ float cos2pi(float rev) { return __builtin_amdgcn_cosf(rev); }
__device__ __forceinline__ float sin2pi(float rev) { return __builtin_amdgcn_sinf(rev); }

// ============ kernel A: fused softplus -> stage-1 DFT (blocks 0..255) + softmax(W) (blocks 256..259) ============
// stage 1: Y[r][t1][k2] = sum_t2 softplus(H)[r][t1+64*t2] * W128^(k2*t2),  8192 = 64(t1) x 128(t2)
// Block b<256 handles r = b>>5, t1 in {2(b&31), 2(b&31)+1}, all k2. Its 256 needed
// softplus values and the 128 distinct twiddles live in LDS.
__global__ __launch_bounds__(256) void k_pre(const float* __restrict__ H,
                                             const float* __restrict__ W) {
    if (blockIdx.x < 256) {
        __shared__ float spl[256];          // spl[h*128+j] = softplus(H[r, 2(b&31)+h + 64*j])
        __shared__ float cs[128], sn[128];  // twiddle table, 128 distinct angles
        int t    = threadIdx.x;
        int b    = blockIdx.x;
        int r    = b >> 5;
        int half = t >> 7;                  // wave-uniform (waves 0,1 -> 0; waves 2,3 -> 1)
        int j    = t & 127;
        int t1   = ((b & 31) << 1) | half;
        float x = H[r * M_ + t1 + (j << 6)];
        spl[half * 128 + j] = (x > 20.f) ? x : log1pf(expf(x));
        if (t < 128) {
            float rev = (float)t * (1.0f / 128.0f);
            cs[t] = cos2pi(rev);
            sn[t] = sin2pi(rev);
        }
        __syncthreads();
        int k2 = j;
        float ar = 0.f, ai = 0.f;
        for (int t2 = 0; t2 < 128; ++t2) {
            float xv = spl[half * 128 + t2];          // wave-uniform -> LDS broadcast
            int id = (k2 * t2) & 127;
            ar = fmaf(xv,  cs[id], ar);               // x * (c - i s)
            ai = fmaf(xv, -sn[id], ai);
        }
        g_Y[b * 256 + t] = make_float2(ar, ai);       // == g_Y[r*8192 + t1*128 + k2]
    } else {
        int n = (blockIdx.x - 256) * 256 + threadIdx.x;
        if (n < N_) {
            float v[RANK_];
            float mx = -1e30f;
#pragma unroll
            for (int r = 0; r < RANK_; ++r) { v[r] = W[n * RANK_ + r]; mx = fmaxf(mx, v[r]); }
            float s = 0.f;
#pragma unroll
            for (int r = 0; r < RANK_; ++r) { v[r] = expf(v[r] - mx); s += v[r]; }
            float inv = 1.f / s;
#pragma unroll
            for (int r = 0; r < RANK_; ++r) g_sw[n * RANK_ + r] = v[r] * inv;
        }
    }
}

// ============ kernel B: stage-2 DFT with rotation recurrence + amp/phase epilogue ============
// Hf[r][k] = sum_t1 Y[r][t1][k&127] * e^{-2pi*i*t1*k/8192}
// Twiddle angle increments by exactly k/8192 revolutions per t1 step -> rotate a
// unit rotor (4 fma) instead of 2 transcendentals per iteration.
__global__ void k_dft2() {
    int tid = blockIdx.x * blockDim.x + threadIdx.x;   // 65536 threads
    int k = tid & 8191;
    int r = tid >> 13;
    int j = k & 127;
    const float2* y = g_Y + r * M_ + j;
    float rev = (float)k * (1.0f / 8192.0f);           // exact in fp32
    float cr = cos2pi(rev), sr = sin2pi(rev);
    float c = 1.f, s = 0.f;                            // rotor at t1 = 0
    float ar = 0.f, ai = 0.f;
    for (int t1 = 0; t1 < 64; ++t1) {
        float2 yv = y[t1 * 128];                       // coalesced (lanes j-consecutive)
        // (yr + i*yi) * (c - i*s)
        ar = fmaf(yv.x, c, ar); ar = fmaf(yv.y, s, ar);
        ai = fmaf(yv.y, c, ai); ai = fmaf(-yv.x, s, ai);
        // angle += rev :  cos(a+b) = c*cr - s*sr ; sin(a+b) = s*cr + c*sr
        float cn = fmaf(c, cr, -(s * sr));
        float sn_ = fmaf(s, cr,  (c * sr));
        c = cn; s = sn_;
    }
    g_Amp[tid] = sqrtf(ar * ar + ai * ai);
    g_Phi[tid] = atan2f(ai, ar) * 0.15915494309189535f;  // /(2pi) -> revolutions
}

// ============ kernel C: out[n,m] = Re(V[n,m]) = sum_r sw[n,r] * A[r,m] * cos(2pi*(tau*f - phi)) ============
// d_out is (N, M) float32 = real part of the complex reference (established R4).
// vf2 math to encourage v_pk_fma_f32; 1 v_cos per element is the trans floor.
#define MT 4   // m-values per thread (float4 store)
#define NT 8   // n-rows per block (A/P L2 traffic halved vs NT=4)
__global__ __launch_bounds__(256) void k_main(const float* __restrict__ tau,
                                              float4* __restrict__ out,
                                              int out_size_floats) {
    int m0 = (blockIdx.x * 256 + threadIdx.x) * MT;
    int n0 = blockIdx.y * NT;
    const float invM = 1.0f / (float)M_;
    vf2 f01 = { (float)m0 * invM,       (float)(m0 + 1) * invM };
    vf2 f23 = { (float)(m0 + 2) * invM, (float)(m0 + 3) * invM };

    vf2 acc01[NT], acc23[NT];
#pragma unroll
    for (int i = 0; i < NT; ++i) { acc01[i] = (vf2){0.f, 0.f}; acc23[i] = (vf2){0.f, 0.f}; }

#pragma unroll
    for (int r = 0; r < RANK_; ++r) {
        float4 A = *reinterpret_cast<const float4*>(&g_Amp[r * M_ + m0]);
        float4 P = *reinterpret_cast<const float4*>(&g_Phi[r * M_ + m0]);
        vf2 A01 = {A.x, A.y}, A23 = {A.z, A.w};
        vf2 nP01 = {-P.x, -P.y}, nP23 = {-P.z, -P.w};
#pragma unroll
        for (int i = 0; i < NT; ++i) {
            float tv = tau [(n0 + i) * RANK_ + r];   // wave-uniform -> s_load
            float wv = g_sw[(n0 + i) * RANK_ + r];
            vf2 tvv  = {tv, tv};
            vf2 wvv  = {wv, wv};
            vf2 wA01 = wvv * A01;
            vf2 wA23 = wvv * A23;
            vf2 a01 = __builtin_elementwise_fma(tvv, f01, nP01);
            vf2 a23 = __builtin_elementwise_fma(tvv, f23, nP23);
            vf2 c01 = { cos2pi(__builtin_amdgcn_fractf(a01.x)),
                        cos2pi(__builtin_amdgcn_fractf(a01.y)) };
            vf2 c23 = { cos2pi(__builtin_amdgcn_fractf(a23.x)),
                        cos2pi(__builtin_amdgcn_fractf(a23.y)) };
            acc01[i] = __builtin_elementwise_fma(wA01, c01, acc01[i]);
            acc23[i] = __builtin_elementwise_fma(wA23, c23, acc23[i]);
        }
    }
    int max_f4 = out_size_floats >> 2;               // guarded stores: no OOB ever
#pragma unroll
    for (int i = 0; i < NT; ++i) {
        int idx = ((n0 + i) * M_ + m0) >> 2;
        if (idx < max_f4) {
            float4 o = { acc01[i].x, acc01[i].y, acc23[i].x, acc23[i].y };
            out[idx] = o;
        }
    }
}

extern "C" void kernel_launch(void* const* d_in, const int* in_sizes, int n_in,
                              void* d_out, int out_size, void* d_ws, size_t ws_size,
                              hipStream_t stream) {
    const float* W   = (const float*)d_in[0];   // (N, RANK)
    const float* H   = (const float*)d_in[1];   // (RANK, M)
    const float* tau = (const float*)d_in[2];   // (N, RANK)

    float4* out = (float4*)d_out;

    k_pre  <<<dim3(256 + N_ / 256),              dim3(256), 0, stream>>>(H, W);
    k_dft2 <<<dim3((RANK_ * M_) / 256),          dim3(256), 0, stream>>>();
    k_main <<<dim3(M_ / (256 * MT), N_ / NT),    dim3(256), 0, stream>>>(tau, out, out_size);
}